// Round 7
// baseline (310.470 us; speedup 1.0000x reference)
//
#include <hip/hip_runtime.h>
#include <math.h>

#define N_NODES 100000
#define N_EDGES 800000
#define F 128
#define NBUCK ((N_NODES + 255) / 256)   // 391 buckets of 256 target nodes
#define NREP 8                          // counter/stage replicas (~1 per XCD)
#define SCAP_R 512                      // staged edges per (bucket,replica): mean 256, +16 sigma
#define CPAD 32                         // counter stride in ints = 128B = own L2 line
#define BSPAN 4096                      // padded CSR span per bucket (mean 2944, +16 sigma)

typedef __attribute__((ext_vector_type(8))) short short8;
typedef __attribute__((ext_vector_type(4))) float floatx4;

__device__ __forceinline__ unsigned short f2bf(float f) {
    unsigned u = __float_as_uint(f);
    u += 0x7fffu + ((u >> 16) & 1u);          // round-to-nearest-even
    return (unsigned short)(u >> 16);
}
__device__ __forceinline__ float bf_lo(unsigned u) { return __uint_as_float(u << 16); }
__device__ __forceinline__ float bf_hi(unsigned u) { return __uint_as_float(u & 0xffff0000u); }
__device__ __forceinline__ unsigned pack2(float a, float b) {
    return (unsigned)f2bf(a) | ((unsigned)f2bf(b) << 16);
}

// ---------------- CSR build: bucketed counting sort, contention-free counters ----------
// Atomics serialize per cache LINE at the coherence point (round-1 lesson: 391
// packed counters = 25 lines = 32k serial ops/line = 282us). Fix: each counter
// gets its own 128B line (CPAD) and is 8-way replicated by blockIdx&7 (~XCD id
// under round-robin dispatch) -> ~256 ops/line, and each replica's stage segment
// is filled from one XCD -> lines fill completely in that L2, no write bounce.

__global__ void k_fill2(const int* __restrict__ row, const int* __restrict__ col,
                        int* __restrict__ bcnt, unsigned* __restrict__ stage) {
    int e = blockIdx.x * blockDim.x + threadIdx.x;
    if (e >= N_EDGES) return;
    int r = row[e], c = col[e];
    int bk = c >> 8;
    int ctr = (bk << 3) | (blockIdx.x & (NREP - 1));
    int p = atomicAdd(&bcnt[ctr * CPAD], 1);
    if (p < SCAP_R)                                // cannot trigger (+16 sigma); guards OOB
        stage[(size_t)ctr * SCAP_R + p] = ((unsigned)(c & 255) << 20) | (unsigned)(r + 1);
}

// Pass 2: one block per bucket. Drain 8 replica segments: LDS histogram -> LDS
// scan of 8-padded counts -> LDS scatter -> coalesced flush. Emits rp2, dinv, dinv2.

__global__ __launch_bounds__(256) void k_build(const int* __restrict__ bcnt,
                                               const unsigned* __restrict__ stage,
                                               unsigned* __restrict__ csr,
                                               int2* __restrict__ rp2,
                                               float* __restrict__ dinv,
                                               float* __restrict__ dinv2) {
    __shared__ int hist[256];
    __shared__ int sc[256];
    __shared__ int cursor[256];
    __shared__ int spanTot;
    __shared__ unsigned img[BSPAN];                // 16 KB bucket-local CSR image
    int bk = blockIdx.x, t = threadIdx.x;
    hist[t] = 0;
    __syncthreads();
#pragma unroll
    for (int rep = 0; rep < NREP; ++rep) {
        int ctr = (bk << 3) | rep;
        int n = bcnt[ctr * CPAD]; n = n < SCAP_R ? n : SCAP_R;
        const unsigned* sp = stage + (size_t)ctr * SCAP_R;
        for (int i = t; i < n; i += 256) atomicAdd(&hist[sp[i] >> 20], 1);
    }
    __syncthreads();
    int cdeg = hist[t];
    int pad = (cdeg + 7) & ~7;                     // rows 8-padded (hop loads uint4 pairs)
    sc[t] = pad;
    __syncthreads();
#pragma unroll
    for (int off = 1; off < 256; off <<= 1) {      // Hillis-Steele inclusive scan
        int u = (t >= off) ? sc[t - off] : 0;
        __syncthreads();
        sc[t] += u;
        __syncthreads();
    }
    int excl = sc[t] - pad;
    if (t == 255) spanTot = sc[255];
    cursor[t] = excl;
    __syncthreads();
    int tot = spanTot;
    int node = bk * 256 + t;
    if (node < N_NODES) {
        int base = bk * BSPAN;
        rp2[node] = (int2){base + excl, base + excl + pad};
        float d = rsqrtf((float)cdeg + 1.0f);      // +1 self-loop
        dinv[node] = d; dinv2[node] = d * d;
    }
    for (int i = t; i < tot; i += 256) img[i] = 0u;   // pad slots -> zero row
    __syncthreads();
#pragma unroll
    for (int rep = 0; rep < NREP; ++rep) {
        int ctr = (bk << 3) | rep;
        int n = bcnt[ctr * CPAD]; n = n < SCAP_R ? n : SCAP_R;
        const unsigned* sp = stage + (size_t)ctr * SCAP_R;
        for (int i = t; i < n; i += 256) {
            unsigned v = sp[i];
            int pos = atomicAdd(&cursor[v >> 20], 1);
            img[pos] = v & 0xFFFFFu;               // r+1 (rows shifted +1)
        }
    }
    __syncthreads();
    unsigned* op = csr + (size_t)bk * BSPAN;
    for (int i = t; i < tot; i += 256) op[i] = img[i];   // coalesced flush
}

// prep: xb[(v+1)] = bf16(dinv[v] * x[v])  (shifted rows; row 0 = zeros).
// Also zeroes row 0 of h1b, and converts W -> bf16 (32 KB) for the GEMM's
// L1-resident direct fragment loads. x is read-once -> nontemporal (keeps L3
// free for h1b/h2b/out). Runs after k_build (needs dinv).
__global__ void k_prep(const floatx4* __restrict__ x, const float* __restrict__ dinv,
                       const float4* __restrict__ W4, uint2* __restrict__ wbf,
                       uint2* __restrict__ xb, uint2* __restrict__ h1b) {
    int i = blockIdx.x * blockDim.x + threadIdx.x;
    if (i < 32) { xb[i] = (uint2){0u, 0u}; h1b[i] = (uint2){0u, 0u}; }
    if (i < 4096) {                            // 4096 float4 = all of W (64 KB)
        float4 wv = W4[i];
        uint2 o; o.x = pack2(wv.x, wv.y); o.y = pack2(wv.z, wv.w);
        wbf[i] = o;                            // row-major bf16 W, 256 B/row
    }
    if (i >= N_NODES * 32) return;
    int node = i >> 5;
    float d = dinv[node];
    floatx4 v = __builtin_nontemporal_load(x + i);   // ext-vector type: builtin-legal
    uint2 o; o.x = pack2(d * v.x, d * v.y); o.y = pack2(d * v.z, d * v.w);
    xb[i + 32] = o;                            // row node+1
}

// ---------------- propagation: weight-free gather, 2 nodes/wave, exact 8-deep ----------------
// acc = y[c] + sum y[r]; out = scale[c] * acc  (scale = dinv^2 for hop1 -> y1,
// dinv for hop2 -> h2). Rows shifted +1; pad entries hit zero row 0 (L1-hot).

__global__ __launch_bounds__(256) void k_hop(const int2* __restrict__ rp2,
                                             const unsigned* __restrict__ csr,
                                             const float* __restrict__ scale,
                                             const uint2* __restrict__ src,
                                             uint2* __restrict__ dst) {
    int wv = (blockIdx.x * blockDim.x + threadIdx.x) >> 6;
    int lane = threadIdx.x & 63;
    int half = lane >> 5, off = lane & 31;
    int node = wv * 2 + half;                       // 50k waves exact
    if (node >= N_NODES) return;
    uint2 u = src[(size_t)(node + 1) * 32 + off];   // own (pre-scaled) row
    float a0 = bf_lo(u.x), a1 = bf_hi(u.x);
    float a2 = bf_lo(u.y), a3 = bf_hi(u.y);
    int2 rp = rp2[node];
    int e = rp.x, end = rp.y;                       // end-e is a multiple of 8
    for (; e < end; e += 8) {
        const uint4* cp = (const uint4*)(csr + e);  // 16B-aligned (8-padded rows)
        uint4 c0 = cp[0], c1 = cp[1];               // 8 indices, broadcast loads
        unsigned idx[8] = {c0.x, c0.y, c0.z, c0.w, c1.x, c1.y, c1.z, c1.w};
#pragma unroll
        for (int j = 0; j < 8; ++j) {
            uint2 v = src[(size_t)idx[j] * 32 + off];
            a0 += bf_lo(v.x); a1 += bf_hi(v.x);
            a2 += bf_lo(v.y); a3 += bf_hi(v.y);
        }
    }
    float s = scale[node];
    uint2 o; o.x = pack2(s * a0, s * a1); o.y = pack2(s * a2, s * a3);
    dst[(size_t)(node + 1) * 32 + off] = o;
}

// ---------------- MFMA GEMM + bias + log_softmax ----------------
// Round-5 lesson: removing LDS staging changed HBM traffic ~2% (92/148 MB vs
// 94/149) -> staging was never the traffic. The 240 MB (vs 77 MB ideal) is the
// out-store stream being L2-allocated (RFO fetch ~51 MB) and re-written ~3x,
// plus h-stream losing its L3 residency. Both streams are strictly
// once-touched here -> nontemporal: stores bypass allocation (no RFO, single
// HBM write), loads don't pollute L1/L2 (wbf stays resident). W fragments read
// directly from the 32 KB L1-resident bf16 image (r4 lesson: per-block LDS
// copies cost more than they save for a 32 KB operand).

__global__ __launch_bounds__(256, 4) void k_gemm_lsm_mfma(const unsigned short* __restrict__ h,
                                                          const unsigned short* __restrict__ wbf,
                                                          const float* __restrict__ b,
                                                          float* __restrict__ out) {
    int tid = threadIdx.x;
    int lane = tid & 63;
    int wave = tid >> 6;
    int m = lane & 15, quad = lane >> 4;

    float bv[8];
#pragma unroll
    for (int t = 0; t < 8; ++t) bv[t] = b[16 * t + m];

    const int ngroups = (N_NODES + 63) / 64;        // 1563 groups of 64 nodes
    for (int g = blockIdx.x; g < ngroups; g += gridDim.x) {
        int gbase = g * 64 + wave * 16;
        int nodeA = gbase + m;
        int node_c = nodeA < N_NODES ? nodeA : N_NODES - 1;
        short8 a[4];
#pragma unroll
        for (int ks = 0; ks < 4; ++ks)
            a[ks] = __builtin_nontemporal_load(
                (const short8*)(h + (size_t)node_c * 128 + ks * 32 + quad * 8));
        floatx4 acc[8];
#pragma unroll
        for (int t = 0; t < 8; ++t) acc[t] = (floatx4){bv[t], bv[t], bv[t], bv[t]};
        // B fragment (t,ks): lane holds W[16t+m][ks*32+quad*8 .. +8) as bf16,
        // loaded straight from the L1-resident 32 KB wbf image.
#pragma unroll
        for (int t = 0; t < 8; ++t) {
#pragma unroll
            for (int ks = 0; ks < 4; ++ks) {
                short8 bf = *(const short8*)(wbf + (size_t)(16 * t + m) * 128 + ks * 32 + quad * 8);
                acc[t] = __builtin_amdgcn_mfma_f32_16x16x32_bf16(a[ks], bf, acc[t], 0, 0, 0);
            }
        }

        // D layout: row = gbase + quad*4 + r, col = 16t + m
#pragma unroll
        for (int r = 0; r < 4; ++r) {
            float mx = acc[0][r];
#pragma unroll
            for (int t = 1; t < 8; ++t) mx = fmaxf(mx, acc[t][r]);
#pragma unroll
            for (int msk = 1; msk < 16; msk <<= 1) mx = fmaxf(mx, __shfl_xor(mx, msk));
            float sm = 0.f;
#pragma unroll
            for (int t = 0; t < 8; ++t) sm += __expf(acc[t][r] - mx);
#pragma unroll
            for (int msk = 1; msk < 16; msk <<= 1) sm += __shfl_xor(sm, msk);
            float l = mx + __logf(sm);
            int rown = gbase + quad * 4 + r;
            if (rown < N_NODES) {
                float* op = out + (size_t)rown * 128 + m;
#pragma unroll
                for (int t = 0; t < 8; ++t)
                    __builtin_nontemporal_store(acc[t][r] - l, op + 16 * t);
            }
        }
    }
}

// ---------------- launch ----------------

extern "C" void kernel_launch(void* const* d_in, const int* in_sizes, int n_in,
                              void* d_out, int out_size, void* d_ws, size_t ws_size,
                              hipStream_t stream) {
    const float* x = (const float*)d_in[0];
    const float* W = (const float*)d_in[1];
    const float* b = (const float*)d_in[2];
    const int* edge = (const int*)d_in[3];
    const int* row = edge;             // source nodes j
    const int* col = edge + N_EDGES;   // target nodes i
    float* out = (float*)d_out;

    // workspace layout (4B word offsets)
    int*      bcnt  = (int*)d_ws;                     // NBUCK*NREP padded ctrs (400KB) - only memset
    float*    dinv  = (float*)(bcnt + NBUCK * NREP * CPAD + 256);
    float*    dinv2 = dinv + 102400;                  // 100k
    int2*     rp2   = (int2*)(dinv2 + 102400);        // 100k (start,end)
    unsigned* csr   = (unsigned*)(rp2 + 102400);      // NBUCK*BSPAN = 1.6M (6.4 MB)
    uint2*    xb    = (uint2*)(csr + (size_t)NBUCK * BSPAN);  // (N+1)*32 uint2 = 25.6 MB
    uint2*    h1b   = xb + 32 * (N_NODES + 1);        // (N+1)*32 uint2
    uint2*    h2b   = xb;                             // reuse: xb dead after hop 1
    // stage aliases h1b past its zero-row (h1b is only written by k_hop #1,
    // which launches after k_build has consumed stage; stream order serializes).
    unsigned* stage = (unsigned*)(h1b + 32);          // NBUCK*NREP*SCAP_R*4 = 6.4 MB
    uint2*    wbf   = h1b + 32 * (N_NODES + 1);       // 4096 uint2 = 32 KB bf16 W

    int nb_edges = (N_EDGES + 255) / 256;
    int nb_prep = (N_NODES * 32 + 255) / 256;         // 12500

    (void)hipMemsetAsync(bcnt, 0, (size_t)NBUCK * NREP * CPAD * 4, stream);  // 400 KB
    k_fill2<<<nb_edges, 256, 0, stream>>>(row, col, bcnt, stage);
    k_build<<<NBUCK, 256, 0, stream>>>(bcnt, stage, csr, rp2, dinv, dinv2);
    k_prep<<<nb_prep, 256, 0, stream>>>((const floatx4*)x, dinv, (const float4*)W, wbf, xb, h1b);

    int hop_blocks = (N_NODES / 2 * 64) / 256;        // 12500: one wave per 2 nodes
    k_hop<<<hop_blocks, 256, 0, stream>>>(rp2, csr, dinv2, xb, h1b);   // -> y1
    k_hop<<<hop_blocks, 256, 0, stream>>>(rp2, csr, dinv, h1b, h2b);   // -> h2

    k_gemm_lsm_mfma<<<1563, 256, 0, stream>>>((const unsigned short*)(h2b + 32),
                                              (const unsigned short*)wbf, b, out);
}

// Round 8
// 300.446 us; speedup vs baseline: 1.0334x; 1.0334x over previous
//
#include <hip/hip_runtime.h>
#include <math.h>

#define N_NODES 100000
#define N_EDGES 800000
#define F 128
#define NBUCK ((N_NODES + 255) / 256)   // 391 buckets of 256 target nodes
#define NREP 8                          // counter/stage replicas (~1 per XCD)
#define SCAP_R 512                      // staged edges per (bucket,replica): mean 256, +16 sigma
#define CPAD 32                         // counter stride in ints = 128B = own L2 line
#define BSPAN 4096                      // padded CSR span per bucket (mean 2944, +16 sigma)

typedef __attribute__((ext_vector_type(8))) short short8;
typedef __attribute__((ext_vector_type(4))) float floatx4;

__device__ __forceinline__ unsigned short f2bf(float f) {
    unsigned u = __float_as_uint(f);
    u += 0x7fffu + ((u >> 16) & 1u);          // round-to-nearest-even
    return (unsigned short)(u >> 16);
}
__device__ __forceinline__ float bf_lo(unsigned u) { return __uint_as_float(u << 16); }
__device__ __forceinline__ float bf_hi(unsigned u) { return __uint_as_float(u & 0xffff0000u); }
__device__ __forceinline__ unsigned pack2(float a, float b) {
    return (unsigned)f2bf(a) | ((unsigned)f2bf(b) << 16);
}

// ---------------- CSR build: bucketed counting sort, contention-free counters ----------
// Atomics serialize per cache LINE at the coherence point (round-1 lesson: 391
// packed counters = 25 lines = 32k serial ops/line = 282us). Fix: each counter
// gets its own 128B line (CPAD) and is 8-way replicated by blockIdx&7 (~XCD id
// under round-robin dispatch) -> ~256 ops/line, and each replica's stage segment
// is filled from one XCD -> lines fill completely in that L2, no write bounce.

__global__ void k_fill2(const int* __restrict__ row, const int* __restrict__ col,
                        int* __restrict__ bcnt, unsigned* __restrict__ stage) {
    int e = blockIdx.x * blockDim.x + threadIdx.x;
    if (e >= N_EDGES) return;
    int r = row[e], c = col[e];
    int bk = c >> 8;
    int ctr = (bk << 3) | (blockIdx.x & (NREP - 1));
    int p = atomicAdd(&bcnt[ctr * CPAD], 1);
    if (p < SCAP_R)                                // cannot trigger (+16 sigma); guards OOB
        stage[(size_t)ctr * SCAP_R + p] = ((unsigned)(c & 255) << 20) | (unsigned)(r + 1);
}

// Pass 2: one block per bucket. Drain 8 replica segments: LDS histogram -> LDS
// scan of 8-padded counts -> LDS scatter -> coalesced flush. Emits rp2, dinv, dinv2.

__global__ __launch_bounds__(256) void k_build(const int* __restrict__ bcnt,
                                               const unsigned* __restrict__ stage,
                                               unsigned* __restrict__ csr,
                                               int2* __restrict__ rp2,
                                               float* __restrict__ dinv,
                                               float* __restrict__ dinv2) {
    __shared__ int hist[256];
    __shared__ int sc[256];
    __shared__ int cursor[256];
    __shared__ int spanTot;
    __shared__ unsigned img[BSPAN];                // 16 KB bucket-local CSR image
    int bk = blockIdx.x, t = threadIdx.x;
    hist[t] = 0;
    __syncthreads();
#pragma unroll
    for (int rep = 0; rep < NREP; ++rep) {
        int ctr = (bk << 3) | rep;
        int n = bcnt[ctr * CPAD]; n = n < SCAP_R ? n : SCAP_R;
        const unsigned* sp = stage + (size_t)ctr * SCAP_R;
        for (int i = t; i < n; i += 256) atomicAdd(&hist[sp[i] >> 20], 1);
    }
    __syncthreads();
    int cdeg = hist[t];
    int pad = (cdeg + 7) & ~7;                     // rows 8-padded (hop loads uint4 pairs)
    sc[t] = pad;
    __syncthreads();
#pragma unroll
    for (int off = 1; off < 256; off <<= 1) {      // Hillis-Steele inclusive scan
        int u = (t >= off) ? sc[t - off] : 0;
        __syncthreads();
        sc[t] += u;
        __syncthreads();
    }
    int excl = sc[t] - pad;
    if (t == 255) spanTot = sc[255];
    cursor[t] = excl;
    __syncthreads();
    int tot = spanTot;
    int node = bk * 256 + t;
    if (node < N_NODES) {
        int base = bk * BSPAN;
        rp2[node] = (int2){base + excl, base + excl + pad};
        float d = rsqrtf((float)cdeg + 1.0f);      // +1 self-loop
        dinv[node] = d; dinv2[node] = d * d;
    }
    for (int i = t; i < tot; i += 256) img[i] = 0u;   // pad slots -> zero row
    __syncthreads();
#pragma unroll
    for (int rep = 0; rep < NREP; ++rep) {
        int ctr = (bk << 3) | rep;
        int n = bcnt[ctr * CPAD]; n = n < SCAP_R ? n : SCAP_R;
        const unsigned* sp = stage + (size_t)ctr * SCAP_R;
        for (int i = t; i < n; i += 256) {
            unsigned v = sp[i];
            int pos = atomicAdd(&cursor[v >> 20], 1);
            img[pos] = v & 0xFFFFFu;               // r+1 (rows shifted +1)
        }
    }
    __syncthreads();
    unsigned* op = csr + (size_t)bk * BSPAN;
    for (int i = t; i < tot; i += 256) op[i] = img[i];   // coalesced flush
}

// prep: xb[(v+1)] = bf16(dinv[v] * x[v])  (shifted rows; row 0 = zeros).
// Also zeroes row 0 of h1b, and converts W -> bf16 (32 KB) for the GEMM's
// L1-resident direct fragment loads. Runs after k_build (needs dinv).
__global__ void k_prep(const float4* __restrict__ x, const float* __restrict__ dinv,
                       const float4* __restrict__ W4, uint2* __restrict__ wbf,
                       uint2* __restrict__ xb, uint2* __restrict__ h1b) {
    int i = blockIdx.x * blockDim.x + threadIdx.x;
    if (i < 32) { xb[i] = (uint2){0u, 0u}; h1b[i] = (uint2){0u, 0u}; }
    if (i < 4096) {                            // 4096 float4 = all of W (64 KB)
        float4 wv = W4[i];
        uint2 o; o.x = pack2(wv.x, wv.y); o.y = pack2(wv.z, wv.w);
        wbf[i] = o;                            // row-major bf16 W, 256 B/row
    }
    if (i >= N_NODES * 32) return;
    int node = i >> 5;
    float d = dinv[node];
    float4 v = x[i];
    uint2 o; o.x = pack2(d * v.x, d * v.y); o.y = pack2(d * v.z, d * v.w);
    xb[i + 32] = o;                            // row node+1
}

// ---------------- propagation: weight-free gather, 2 nodes/wave, exact 8-deep ----------------
// acc = y[c] + sum y[r]; out = scale[c] * acc  (scale = dinv^2 for hop1 -> y1,
// dinv for hop2 -> h2). Rows shifted +1; pad entries hit zero row 0 (L1-hot).

__global__ __launch_bounds__(256) void k_hop(const int2* __restrict__ rp2,
                                             const unsigned* __restrict__ csr,
                                             const float* __restrict__ scale,
                                             const uint2* __restrict__ src,
                                             uint2* __restrict__ dst) {
    int wv = (blockIdx.x * blockDim.x + threadIdx.x) >> 6;
    int lane = threadIdx.x & 63;
    int half = lane >> 5, off = lane & 31;
    int node = wv * 2 + half;                       // 50k waves exact
    if (node >= N_NODES) return;
    uint2 u = src[(size_t)(node + 1) * 32 + off];   // own (pre-scaled) row
    float a0 = bf_lo(u.x), a1 = bf_hi(u.x);
    float a2 = bf_lo(u.y), a3 = bf_hi(u.y);
    int2 rp = rp2[node];
    int e = rp.x, end = rp.y;                       // end-e is a multiple of 8
    for (; e < end; e += 8) {
        const uint4* cp = (const uint4*)(csr + e);  // 16B-aligned (8-padded rows)
        uint4 c0 = cp[0], c1 = cp[1];               // 8 indices, broadcast loads
        unsigned idx[8] = {c0.x, c0.y, c0.z, c0.w, c1.x, c1.y, c1.z, c1.w};
#pragma unroll
        for (int j = 0; j < 8; ++j) {
            uint2 v = src[(size_t)idx[j] * 32 + off];
            a0 += bf_lo(v.x); a1 += bf_hi(v.x);
            a2 += bf_lo(v.y); a3 += bf_hi(v.y);
        }
    }
    float s = scale[node];
    uint2 o; o.x = pack2(s * a0, s * a1); o.y = pack2(s * a2, s * a3);
    dst[(size_t)(node + 1) * 32 + off] = o;
}

// ---------------- MFMA GEMM + bias + log_softmax ----------------
// Round-7 lesson: nontemporal stores made WRITE 148->203 MB (64B half-line
// stores go to memory unmerged) -> reverted. Round-2 evidence: with low
// concurrency the same kernel hit near-ideal traffic (FETCH 13 / WRITE 50 MB),
// so the 92/148 MB at 4 blocks/CU is the epilogue's 4x-scattered 64B
// half-line stores overflowing TCC's merge window -> RFO fetch + multi-
// writeback. Fix is structural: stage each wave's 16 output rows (8 KB) in
// LDS, flush with per-wave float4 stores (64 lanes = 1 KB contiguous, every
// 128B line written whole by ONE instruction). No barrier (wave owns its
// rows). Plain cached h loads keep the L3-dirty h2b hits.

__global__ __launch_bounds__(256, 4) void k_gemm_lsm_mfma(const unsigned short* __restrict__ h,
                                                          const unsigned short* __restrict__ wbf,
                                                          const float* __restrict__ b,
                                                          float* __restrict__ out) {
    __shared__ float olds[64 * 132];               // 33.8 KB; +4 pad per row
    int tid = threadIdx.x;
    int lane = tid & 63;
    int wave = tid >> 6;
    int m = lane & 15, quad = lane >> 4;

    float bv[8];
#pragma unroll
    for (int t = 0; t < 8; ++t) bv[t] = b[16 * t + m];

    const int ngroups = (N_NODES + 63) / 64;        // 1563 groups of 64 nodes
    for (int g = blockIdx.x; g < ngroups; g += gridDim.x) {
        int gbase = g * 64 + wave * 16;
        int nodeA = gbase + m;
        int node_c = nodeA < N_NODES ? nodeA : N_NODES - 1;
        short8 a[4];
#pragma unroll
        for (int ks = 0; ks < 4; ++ks)
            a[ks] = *(const short8*)(h + (size_t)node_c * 128 + ks * 32 + quad * 8);
        floatx4 acc[8];
#pragma unroll
        for (int t = 0; t < 8; ++t) acc[t] = (floatx4){bv[t], bv[t], bv[t], bv[t]};
        // B fragment (t,ks): lane holds W[16t+m][ks*32+quad*8 .. +8) as bf16,
        // loaded straight from the L1-resident 32 KB wbf image.
#pragma unroll
        for (int t = 0; t < 8; ++t) {
#pragma unroll
            for (int ks = 0; ks < 4; ++ks) {
                short8 bf = *(const short8*)(wbf + (size_t)(16 * t + m) * 128 + ks * 32 + quad * 8);
                acc[t] = __builtin_amdgcn_mfma_f32_16x16x32_bf16(a[ks], bf, acc[t], 0, 0, 0);
            }
        }

        // D layout: row = gbase + quad*4 + r, col = 16t + m.
        // log-softmax per row, result -> LDS (banks: 2-way alias = free).
#pragma unroll
        for (int r = 0; r < 4; ++r) {
            float mx = acc[0][r];
#pragma unroll
            for (int t = 1; t < 8; ++t) mx = fmaxf(mx, acc[t][r]);
#pragma unroll
            for (int msk = 1; msk < 16; msk <<= 1) mx = fmaxf(mx, __shfl_xor(mx, msk));
            float sm = 0.f;
#pragma unroll
            for (int t = 0; t < 8; ++t) sm += __expf(acc[t][r] - mx);
#pragma unroll
            for (int msk = 1; msk < 16; msk <<= 1) sm += __shfl_xor(sm, msk);
            float l = mx + __logf(sm);
            float* lp = olds + (wave * 16 + quad * 4 + r) * 132 + m;
#pragma unroll
            for (int t = 0; t < 8; ++t) lp[16 * t] = acc[t][r] - l;
        }
        // flush: wave flushes its own 16 rows; 64 lanes x float4 = 1 KB
        // contiguous per inst = 8 whole 128B lines. No __syncthreads needed.
#pragma unroll
        for (int it = 0; it < 8; ++it) {
            int lr = it * 2 + (lane >> 5);          // local row 0..15
            int c4 = lane & 31;                     // float4 column
            int grow = gbase + lr;
            floatx4 v = *(const floatx4*)(olds + (wave * 16 + lr) * 132 + c4 * 4);
            if (grow < N_NODES)
                *(floatx4*)(out + (size_t)grow * 128 + c4 * 4) = v;
        }
    }
}

// ---------------- launch ----------------

extern "C" void kernel_launch(void* const* d_in, const int* in_sizes, int n_in,
                              void* d_out, int out_size, void* d_ws, size_t ws_size,
                              hipStream_t stream) {
    const float* x = (const float*)d_in[0];
    const float* W = (const float*)d_in[1];
    const float* b = (const float*)d_in[2];
    const int* edge = (const int*)d_in[3];
    const int* row = edge;             // source nodes j
    const int* col = edge + N_EDGES;   // target nodes i
    float* out = (float*)d_out;

    // workspace layout (4B word offsets)
    int*      bcnt  = (int*)d_ws;                     // NBUCK*NREP padded ctrs (400KB) - only memset
    float*    dinv  = (float*)(bcnt + NBUCK * NREP * CPAD + 256);
    float*    dinv2 = dinv + 102400;                  // 100k
    int2*     rp2   = (int2*)(dinv2 + 102400);        // 100k (start,end)
    unsigned* csr   = (unsigned*)(rp2 + 102400);      // NBUCK*BSPAN = 1.6M (6.4 MB)
    uint2*    xb    = (uint2*)(csr + (size_t)NBUCK * BSPAN);  // (N+1)*32 uint2 = 25.6 MB
    uint2*    h1b   = xb + 32 * (N_NODES + 1);        // (N+1)*32 uint2
    uint2*    h2b   = xb;                             // reuse: xb dead after hop 1
    // stage aliases h1b past its zero-row (h1b is only written by k_hop #1,
    // which launches after k_build has consumed stage; stream order serializes).
    unsigned* stage = (unsigned*)(h1b + 32);          // NBUCK*NREP*SCAP_R*4 = 6.4 MB
    uint2*    wbf   = h1b + 32 * (N_NODES + 1);       // 4096 uint2 = 32 KB bf16 W

    int nb_edges = (N_EDGES + 255) / 256;
    int nb_prep = (N_NODES * 32 + 255) / 256;         // 12500

    (void)hipMemsetAsync(bcnt, 0, (size_t)NBUCK * NREP * CPAD * 4, stream);  // 400 KB
    k_fill2<<<nb_edges, 256, 0, stream>>>(row, col, bcnt, stage);
    k_build<<<NBUCK, 256, 0, stream>>>(bcnt, stage, csr, rp2, dinv, dinv2);
    k_prep<<<nb_prep, 256, 0, stream>>>((const float4*)x, dinv, (const float4*)W, wbf, xb, h1b);

    int hop_blocks = (N_NODES / 2 * 64) / 256;        // 12500: one wave per 2 nodes
    k_hop<<<hop_blocks, 256, 0, stream>>>(rp2, csr, dinv2, xb, h1b);   // -> y1
    k_hop<<<hop_blocks, 256, 0, stream>>>(rp2, csr, dinv, h1b, h2b);   // -> h2

    k_gemm_lsm_mfma<<<1563, 256, 0, stream>>>((const unsigned short*)(h2b + 32),
                                              (const unsigned short*)wbf, b, out);
}

// Round 9
// 245.479 us; speedup vs baseline: 1.2648x; 1.2239x over previous
//
#include <hip/hip_runtime.h>
#include <math.h>

#define N_NODES 100000
#define N_EDGES 800000
#define F 128
#define NBUCK ((N_NODES + 255) / 256)   // 391 buckets of 256 target nodes
#define NREP 8                          // counter/stage replicas (~1 per XCD)
#define SCAP_R 512                      // staged edges per (bucket,replica): mean 256, +16 sigma
#define CPAD 32                         // counter stride in ints = 128B = own L2 line
#define BSPAN 4096                      // padded CSR span per bucket (mean 2944, +16 sigma)

typedef __attribute__((ext_vector_type(8))) short short8;
typedef __attribute__((ext_vector_type(4))) float floatx4;

__device__ __forceinline__ unsigned short f2bf(float f) {
    unsigned u = __float_as_uint(f);
    u += 0x7fffu + ((u >> 16) & 1u);          // round-to-nearest-even
    return (unsigned short)(u >> 16);
}
__device__ __forceinline__ float bf_lo(unsigned u) { return __uint_as_float(u << 16); }
__device__ __forceinline__ float bf_hi(unsigned u) { return __uint_as_float(u & 0xffff0000u); }
__device__ __forceinline__ unsigned pack2(float a, float b) {
    return (unsigned)f2bf(a) | ((unsigned)f2bf(b) << 16);
}

// ---------------- CSR build: bucketed counting sort, contention-free counters ----------
// Atomics serialize per cache LINE at the coherence point (round-1 lesson: 391
// packed counters = 25 lines = 32k serial ops/line = 282us). Fix: each counter
// gets its own 128B line (CPAD) and is 8-way replicated by blockIdx&7 (~XCD id
// under round-robin dispatch) -> ~256 ops/line, and each replica's stage segment
// is filled from one XCD -> lines fill completely in that L2, no write bounce.

__global__ void k_fill2(const int* __restrict__ row, const int* __restrict__ col,
                        int* __restrict__ bcnt, unsigned* __restrict__ stage) {
    int e = blockIdx.x * blockDim.x + threadIdx.x;
    if (e >= N_EDGES) return;
    int r = row[e], c = col[e];
    int bk = c >> 8;
    int ctr = (bk << 3) | (blockIdx.x & (NREP - 1));
    int p = atomicAdd(&bcnt[ctr * CPAD], 1);
    if (p < SCAP_R)                                // cannot trigger (+16 sigma); guards OOB
        stage[(size_t)ctr * SCAP_R + p] = ((unsigned)(c & 255) << 20) | (unsigned)(r + 1);
}

// Pass 2: one block per bucket. Drain 8 replica segments: LDS histogram -> LDS
// scan of 8-padded counts -> LDS scatter -> coalesced flush. Emits rp2, dinv, dinv2.

__global__ __launch_bounds__(256) void k_build(const int* __restrict__ bcnt,
                                               const unsigned* __restrict__ stage,
                                               unsigned* __restrict__ csr,
                                               int2* __restrict__ rp2,
                                               float* __restrict__ dinv,
                                               float* __restrict__ dinv2) {
    __shared__ int hist[256];
    __shared__ int sc[256];
    __shared__ int cursor[256];
    __shared__ int spanTot;
    __shared__ unsigned img[BSPAN];                // 16 KB bucket-local CSR image
    int bk = blockIdx.x, t = threadIdx.x;
    hist[t] = 0;
    __syncthreads();
#pragma unroll
    for (int rep = 0; rep < NREP; ++rep) {
        int ctr = (bk << 3) | rep;
        int n = bcnt[ctr * CPAD]; n = n < SCAP_R ? n : SCAP_R;
        const unsigned* sp = stage + (size_t)ctr * SCAP_R;
        for (int i = t; i < n; i += 256) atomicAdd(&hist[sp[i] >> 20], 1);
    }
    __syncthreads();
    int cdeg = hist[t];
    int pad = (cdeg + 7) & ~7;                     // rows 8-padded (hop loads uint4 pairs)
    sc[t] = pad;
    __syncthreads();
#pragma unroll
    for (int off = 1; off < 256; off <<= 1) {      // Hillis-Steele inclusive scan
        int u = (t >= off) ? sc[t - off] : 0;
        __syncthreads();
        sc[t] += u;
        __syncthreads();
    }
    int excl = sc[t] - pad;
    if (t == 255) spanTot = sc[255];
    cursor[t] = excl;
    __syncthreads();
    int tot = spanTot;
    int node = bk * 256 + t;
    if (node < N_NODES) {
        int base = bk * BSPAN;
        rp2[node] = (int2){base + excl, base + excl + pad};
        float d = rsqrtf((float)cdeg + 1.0f);      // +1 self-loop
        dinv[node] = d; dinv2[node] = d * d;
    }
    for (int i = t; i < tot; i += 256) img[i] = 0u;   // pad slots -> zero row
    __syncthreads();
#pragma unroll
    for (int rep = 0; rep < NREP; ++rep) {
        int ctr = (bk << 3) | rep;
        int n = bcnt[ctr * CPAD]; n = n < SCAP_R ? n : SCAP_R;
        const unsigned* sp = stage + (size_t)ctr * SCAP_R;
        for (int i = t; i < n; i += 256) {
            unsigned v = sp[i];
            int pos = atomicAdd(&cursor[v >> 20], 1);
            img[pos] = v & 0xFFFFFu;               // r+1 (rows shifted +1)
        }
    }
    __syncthreads();
    unsigned* op = csr + (size_t)bk * BSPAN;
    for (int i = t; i < tot; i += 256) op[i] = img[i];   // coalesced flush
}

// prep: xb[(v+1)] = bf16(dinv[v] * x[v])  (shifted rows; row 0 = zeros).
// Also zeroes row 0 of h1b, and converts W -> bf16 (32 KB) for the GEMM's
// direct fragment loads. Runs after k_build (needs dinv).
__global__ void k_prep(const float4* __restrict__ x, const float* __restrict__ dinv,
                       const float4* __restrict__ W4, uint2* __restrict__ wbf,
                       uint2* __restrict__ xb, uint2* __restrict__ h1b) {
    int i = blockIdx.x * blockDim.x + threadIdx.x;
    if (i < 32) { xb[i] = (uint2){0u, 0u}; h1b[i] = (uint2){0u, 0u}; }
    if (i < 4096) {                            // 4096 float4 = all of W (64 KB)
        float4 wv = W4[i];
        uint2 o; o.x = pack2(wv.x, wv.y); o.y = pack2(wv.z, wv.w);
        wbf[i] = o;                            // row-major bf16 W, 256 B/row
    }
    if (i >= N_NODES * 32) return;
    int node = i >> 5;
    float d = dinv[node];
    float4 v = x[i];
    uint2 o; o.x = pack2(d * v.x, d * v.y); o.y = pack2(d * v.z, d * v.w);
    xb[i + 32] = o;                            // row node+1
}

// ---------------- propagation: weight-free gather, 2 nodes/wave, exact 8-deep ----------------
// acc = y[c] + sum y[r]; out = scale[c] * acc  (scale = dinv^2 for hop1 -> y1,
// dinv for hop2 -> h2). Rows shifted +1; pad entries hit zero row 0 (L1-hot).

__global__ __launch_bounds__(256) void k_hop(const int2* __restrict__ rp2,
                                             const unsigned* __restrict__ csr,
                                             const float* __restrict__ scale,
                                             const uint2* __restrict__ src,
                                             uint2* __restrict__ dst) {
    int wv = (blockIdx.x * blockDim.x + threadIdx.x) >> 6;
    int lane = threadIdx.x & 63;
    int half = lane >> 5, off = lane & 31;
    int node = wv * 2 + half;                       // 50k waves exact
    if (node >= N_NODES) return;
    uint2 u = src[(size_t)(node + 1) * 32 + off];   // own (pre-scaled) row
    float a0 = bf_lo(u.x), a1 = bf_hi(u.x);
    float a2 = bf_lo(u.y), a3 = bf_hi(u.y);
    int2 rp = rp2[node];
    int e = rp.x, end = rp.y;                       // end-e is a multiple of 8
    for (; e < end; e += 8) {
        const uint4* cp = (const uint4*)(csr + e);  // 16B-aligned (8-padded rows)
        uint4 c0 = cp[0], c1 = cp[1];               // 8 indices, broadcast loads
        unsigned idx[8] = {c0.x, c0.y, c0.z, c0.w, c1.x, c1.y, c1.z, c1.w};
#pragma unroll
        for (int j = 0; j < 8; ++j) {
            uint2 v = src[(size_t)idx[j] * 32 + off];
            a0 += bf_lo(v.x); a1 += bf_hi(v.x);
            a2 += bf_lo(v.y); a3 += bf_hi(v.y);
        }
    }
    float s = scale[node];
    uint2 o; o.x = pack2(s * a0, s * a1); o.y = pack2(s * a2, s * a3);
    dst[(size_t)(node + 1) * 32 + off] = o;
}

// ---------------- MFMA GEMM + bias + log_softmax ----------------
// Rounds 4-8 empirical law: this kernel's HBM-visible traffic scales with GRID
// SIZE, not store shape (512: 63 MB ideal / 1024: 242 MB / 1563: 306 MB;
// identical at scattered, nontemporal, and LDS-staged full-line stores). The
// concurrency-driven traffic penalty exceeds any latency-hiding gain, so the
// minimum-traffic point grid=512 (2 blocks/CU) is the operating point - the
// r2 config, which measured 52.6us with FETCH 13 / WRITE 50 MB. Kept from the
// detour: B fragments read directly from the pre-converted bf16 wbf image
// (cheaper setup than rebuilding fragments from f32 W per block).

__global__ __launch_bounds__(256) void k_gemm_lsm_mfma(const unsigned short* __restrict__ h,
                                                       const unsigned short* __restrict__ wbf,
                                                       const float* __restrict__ b,
                                                       float* __restrict__ out) {
    int tid = threadIdx.x;
    int lane = tid & 63;
    int wave = tid >> 6;
    int m = lane & 15, quad = lane >> 4;

    float bv[8];
#pragma unroll
    for (int t = 0; t < 8; ++t) bv[t] = b[16 * t + m];

    const int ngroups = (N_NODES + 63) / 64;        // 1563 groups of 64 nodes
    for (int g = blockIdx.x; g < ngroups; g += gridDim.x) {
        int gbase = g * 64 + wave * 16;
        int nodeA = gbase + m;
        int node_c = nodeA < N_NODES ? nodeA : N_NODES - 1;
        short8 a[4];
#pragma unroll
        for (int ks = 0; ks < 4; ++ks)
            a[ks] = *(const short8*)(h + (size_t)node_c * 128 + ks * 32 + quad * 8);
        floatx4 acc[8];
#pragma unroll
        for (int t = 0; t < 8; ++t) acc[t] = (floatx4){bv[t], bv[t], bv[t], bv[t]};
        // B fragment (t,ks): lane holds W[16t+m][ks*32+quad*8 .. +8) as bf16,
        // read from the 32 KB wbf image (L1/L2-hot across groups).
#pragma unroll
        for (int t = 0; t < 8; ++t) {
#pragma unroll
            for (int ks = 0; ks < 4; ++ks) {
                short8 bf = *(const short8*)(wbf + (size_t)(16 * t + m) * 128 + ks * 32 + quad * 8);
                acc[t] = __builtin_amdgcn_mfma_f32_16x16x32_bf16(a[ks], bf, acc[t], 0, 0, 0);
            }
        }

        // D layout: row = gbase + quad*4 + r, col = 16t + m
#pragma unroll
        for (int r = 0; r < 4; ++r) {
            float mx = acc[0][r];
#pragma unroll
            for (int t = 1; t < 8; ++t) mx = fmaxf(mx, acc[t][r]);
#pragma unroll
            for (int msk = 1; msk < 16; msk <<= 1) mx = fmaxf(mx, __shfl_xor(mx, msk));
            float sm = 0.f;
#pragma unroll
            for (int t = 0; t < 8; ++t) sm += __expf(acc[t][r] - mx);
#pragma unroll
            for (int msk = 1; msk < 16; msk <<= 1) sm += __shfl_xor(sm, msk);
            float l = mx + __logf(sm);
            int rown = gbase + quad * 4 + r;
            if (rown < N_NODES) {
                float* op = out + (size_t)rown * 128 + m;
#pragma unroll
                for (int t = 0; t < 8; ++t) op[16 * t] = acc[t][r] - l;
            }
        }
    }
}

// ---------------- launch ----------------

extern "C" void kernel_launch(void* const* d_in, const int* in_sizes, int n_in,
                              void* d_out, int out_size, void* d_ws, size_t ws_size,
                              hipStream_t stream) {
    const float* x = (const float*)d_in[0];
    const float* W = (const float*)d_in[1];
    const float* b = (const float*)d_in[2];
    const int* edge = (const int*)d_in[3];
    const int* row = edge;             // source nodes j
    const int* col = edge + N_EDGES;   // target nodes i
    float* out = (float*)d_out;

    // workspace layout (4B word offsets)
    int*      bcnt  = (int*)d_ws;                     // NBUCK*NREP padded ctrs (400KB) - only memset
    float*    dinv  = (float*)(bcnt + NBUCK * NREP * CPAD + 256);
    float*    dinv2 = dinv + 102400;                  // 100k
    int2*     rp2   = (int2*)(dinv2 + 102400);        // 100k (start,end)
    unsigned* csr   = (unsigned*)(rp2 + 102400);      // NBUCK*BSPAN = 1.6M (6.4 MB)
    uint2*    xb    = (uint2*)(csr + (size_t)NBUCK * BSPAN);  // (N+1)*32 uint2 = 25.6 MB
    uint2*    h1b   = xb + 32 * (N_NODES + 1);        // (N+1)*32 uint2
    uint2*    h2b   = xb;                             // reuse: xb dead after hop 1
    // stage aliases h1b past its zero-row (h1b is only written by k_hop #1,
    // which launches after k_build has consumed stage; stream order serializes).
    unsigned* stage = (unsigned*)(h1b + 32);          // NBUCK*NREP*SCAP_R*4 = 6.4 MB
    uint2*    wbf   = h1b + 32 * (N_NODES + 1);       // 4096 uint2 = 32 KB bf16 W

    int nb_edges = (N_EDGES + 255) / 256;
    int nb_prep = (N_NODES * 32 + 255) / 256;         // 12500

    (void)hipMemsetAsync(bcnt, 0, (size_t)NBUCK * NREP * CPAD * 4, stream);  // 400 KB
    k_fill2<<<nb_edges, 256, 0, stream>>>(row, col, bcnt, stage);
    k_build<<<NBUCK, 256, 0, stream>>>(bcnt, stage, csr, rp2, dinv, dinv2);
    k_prep<<<nb_prep, 256, 0, stream>>>((const float4*)x, dinv, (const float4*)W, wbf, xb, h1b);

    int hop_blocks = (N_NODES / 2 * 64) / 256;        // 12500: one wave per 2 nodes
    k_hop<<<hop_blocks, 256, 0, stream>>>(rp2, csr, dinv2, xb, h1b);   // -> y1
    k_hop<<<hop_blocks, 256, 0, stream>>>(rp2, csr, dinv, h1b, h2b);   // -> h2

    k_gemm_lsm_mfma<<<512, 256, 0, stream>>>((const unsigned short*)(h2b + 32),
                                             (const unsigned short*)wbf, b, out);
}

// Round 10
// 219.143 us; speedup vs baseline: 1.4167x; 1.1202x over previous
//
#include <hip/hip_runtime.h>
#include <math.h>

#define N_NODES 100000
#define N_EDGES 800000
#define F 128
#define NBUCK ((N_NODES + 255) / 256)   // 391 buckets of 256 target nodes
#define CPAD 32                         // counter stride in ints = 128B = own L2 line
#define SCAP 3072                       // per-bucket stage capacity (mean 2048, +22 sigma)
#define BSPAN 4096                      // padded CSR span per bucket (mean 2944, +25 sigma)
#define EPB 2048                        // edges per k_fill3 block
#define FILL_BLOCKS ((N_EDGES + EPB - 1) / EPB)   // 391

typedef __attribute__((ext_vector_type(8))) short short8;
typedef __attribute__((ext_vector_type(4))) float floatx4;

__device__ __forceinline__ unsigned short f2bf(float f) {
    unsigned u = __float_as_uint(f);
    u += 0x7fffu + ((u >> 16) & 1u);          // round-to-nearest-even
    return (unsigned short)(u >> 16);
}
__device__ __forceinline__ float bf_lo(unsigned u) { return __uint_as_float(u << 16); }
__device__ __forceinline__ float bf_hi(unsigned u) { return __uint_as_float(u & 0xffff0000u); }
__device__ __forceinline__ unsigned pack2(float a, float b) {
    return (unsigned)f2bf(a) | ((unsigned)f2bf(b) << 16);
}

// ---------------- CSR build: block-aggregated bucketed counting sort ----------------
// Round-9 lesson: with padded+replicated counters, per-line serialization is
// ~2us, yet k_fill2 took 42us at VALUBusy 0.8% -> the cost is the COUNT of
// fully-divergent small ops (64 atomic lines + 64 store lines per wave).
// k_fill3 amortizes: each block LDS-counting-sorts 2048 edges by bucket
// (the k_build pattern), then does ONE global atomicAdd per (block,bucket)
// (~153k total, 5.3x fewer) and flushes contiguous bucket-runs (mean 5.2
// entries) so stage stores coalesce within runs.

__global__ __launch_bounds__(256) void k_fill3(const int* __restrict__ row,
                                               const int* __restrict__ col,
                                               int* __restrict__ bcnt,
                                               unsigned* __restrict__ stage) {
    __shared__ int hist[512];                  // histogram, then reused as cursor
    __shared__ int base[512];                  // exclusive prefix (block-local)
    __shared__ int gpos[NBUCK];                // global base per bucket
    __shared__ int sA[256], sB[256];
    __shared__ unsigned buf[EPB];              // block-locally sorted entries
    __shared__ unsigned short bkt[EPB];        // bucket of each sorted slot
    int t = threadIdx.x, blk = blockIdx.x;
    int e0 = blk * EPB;
    int nedge = N_EDGES - e0; if (nedge > EPB) nedge = EPB;

    hist[t] = 0; hist[256 + t] = 0;
    __syncthreads();

    int myb[8]; unsigned myv[8];
#pragma unroll
    for (int k = 0; k < 8; ++k) {
        int i = t + k * 256;                   // coalesced within wave
        myb[k] = -1;
        if (i < nedge) {
            int e = e0 + i;
            int r = row[e], c = col[e];
            int bk = c >> 8;
            myb[k] = bk;
            myv[k] = ((unsigned)(c & 255) << 20) | (unsigned)(r + 1);
            atomicAdd(&hist[bk], 1);
        }
    }
    __syncthreads();

    // exclusive scan over 512 (two sequential 256-wide Hillis-Steele scans)
    int v0 = hist[t], v1 = hist[256 + t];
    sA[t] = v0; __syncthreads();
#pragma unroll
    for (int off = 1; off < 256; off <<= 1) {
        int u = (t >= off) ? sA[t - off] : 0;
        __syncthreads(); sA[t] += u; __syncthreads();
    }
    int tot0 = sA[255];
    sB[t] = v1; __syncthreads();
#pragma unroll
    for (int off = 1; off < 256; off <<= 1) {
        int u = (t >= off) ? sB[t - off] : 0;
        __syncthreads(); sB[t] += u; __syncthreads();
    }
    base[t] = sA[t] - v0;
    base[256 + t] = tot0 + sB[t] - v1;
    __syncthreads();
    hist[t] = base[t]; hist[256 + t] = base[256 + t];   // cursor = base
    __syncthreads();

    // scatter into block-local sorted order
#pragma unroll
    for (int k = 0; k < 8; ++k) {
        if (myb[k] >= 0) {
            int pos = atomicAdd(&hist[myb[k]], 1);
            buf[pos] = myv[k];
            bkt[pos] = (unsigned short)myb[k];
        }
    }
    __syncthreads();

    // one global atomic per touched bucket (counters on own 128B lines)
    for (int i = t; i < NBUCK; i += 256) {
        int cnt = hist[i] - base[i];
        gpos[i] = cnt > 0 ? atomicAdd(&bcnt[i * CPAD], cnt) : 0;
    }
    __syncthreads();

    // flush runs: consecutive i in a run -> consecutive global addresses
    for (int i = t; i < nedge; i += 256) {
        int bk = bkt[i];
        int op = gpos[bk] + (i - base[bk]);
        if (op < SCAP)                          // +22 sigma; guards OOB
            stage[(size_t)bk * SCAP + op] = buf[i];
    }
}

// Pass 2: one block per bucket. Drain the single stage segment: LDS histogram ->
// LDS scan of 8-padded counts -> LDS scatter -> coalesced flush. Emits rp2, dinv, dinv2.

__global__ __launch_bounds__(256) void k_build(const int* __restrict__ bcnt,
                                               const unsigned* __restrict__ stage,
                                               unsigned* __restrict__ csr,
                                               int2* __restrict__ rp2,
                                               float* __restrict__ dinv,
                                               float* __restrict__ dinv2) {
    __shared__ int hist[256];
    __shared__ int sc[256];
    __shared__ int cursor[256];
    __shared__ int spanTot;
    __shared__ unsigned img[BSPAN];                // 16 KB bucket-local CSR image
    int bk = blockIdx.x, t = threadIdx.x;
    int n = bcnt[bk * CPAD]; n = n < SCAP ? n : SCAP;
    const unsigned* sp = stage + (size_t)bk * SCAP;
    hist[t] = 0;
    __syncthreads();
    for (int i = t; i < n; i += 256) atomicAdd(&hist[sp[i] >> 20], 1);
    __syncthreads();
    int cdeg = hist[t];
    int pad = (cdeg + 7) & ~7;                     // rows 8-padded (hop loads uint4 pairs)
    sc[t] = pad;
    __syncthreads();
#pragma unroll
    for (int off = 1; off < 256; off <<= 1) {      // Hillis-Steele inclusive scan
        int u = (t >= off) ? sc[t - off] : 0;
        __syncthreads();
        sc[t] += u;
        __syncthreads();
    }
    int excl = sc[t] - pad;
    if (t == 255) spanTot = sc[255];
    cursor[t] = excl;
    __syncthreads();
    int tot = spanTot;
    int node = bk * 256 + t;
    if (node < N_NODES) {
        int base = bk * BSPAN;
        rp2[node] = (int2){base + excl, base + excl + pad};
        float d = rsqrtf((float)cdeg + 1.0f);      // +1 self-loop
        dinv[node] = d; dinv2[node] = d * d;
    }
    for (int i = t; i < tot; i += 256) img[i] = 0u;   // pad slots -> zero row
    __syncthreads();
    for (int i = t; i < n; i += 256) {
        unsigned v = sp[i];
        int pos = atomicAdd(&cursor[v >> 20], 1);
        img[pos] = v & 0xFFFFFu;                   // r+1 (rows shifted +1)
    }
    __syncthreads();
    unsigned* op = csr + (size_t)bk * BSPAN;
    for (int i = t; i < tot; i += 256) op[i] = img[i];   // coalesced flush
}

// prep: xb[(v+1)] = bf16(dinv[v] * x[v])  (shifted rows; row 0 = zeros).
// Also zeroes row 0 of h1b, and converts W -> bf16 (32 KB) for the GEMM's
// direct fragment loads. Runs after k_build (needs dinv).
__global__ void k_prep(const float4* __restrict__ x, const float* __restrict__ dinv,
                       const float4* __restrict__ W4, uint2* __restrict__ wbf,
                       uint2* __restrict__ xb, uint2* __restrict__ h1b) {
    int i = blockIdx.x * blockDim.x + threadIdx.x;
    if (i < 32) { xb[i] = (uint2){0u, 0u}; h1b[i] = (uint2){0u, 0u}; }
    if (i < 4096) {                            // 4096 float4 = all of W (64 KB)
        float4 wv = W4[i];
        uint2 o; o.x = pack2(wv.x, wv.y); o.y = pack2(wv.z, wv.w);
        wbf[i] = o;                            // row-major bf16 W, 256 B/row
    }
    if (i >= N_NODES * 32) return;
    int node = i >> 5;
    float d = dinv[node];
    float4 v = x[i];
    uint2 o; o.x = pack2(d * v.x, d * v.y); o.y = pack2(d * v.z, d * v.w);
    xb[i + 32] = o;                            // row node+1
}

// ---------------- propagation: weight-free gather, 2 nodes/wave, exact 8-deep ----------------
// acc = y[c] + sum y[r]; out = scale[c] * acc  (scale = dinv^2 for hop1 -> y1,
// dinv for hop2 -> h2). Rows shifted +1; pad entries hit zero row 0 (L1-hot).

__global__ __launch_bounds__(256) void k_hop(const int2* __restrict__ rp2,
                                             const unsigned* __restrict__ csr,
                                             const float* __restrict__ scale,
                                             const uint2* __restrict__ src,
                                             uint2* __restrict__ dst) {
    int wv = (blockIdx.x * blockDim.x + threadIdx.x) >> 6;
    int lane = threadIdx.x & 63;
    int half = lane >> 5, off = lane & 31;
    int node = wv * 2 + half;                       // 50k waves exact
    if (node >= N_NODES) return;
    uint2 u = src[(size_t)(node + 1) * 32 + off];   // own (pre-scaled) row
    float a0 = bf_lo(u.x), a1 = bf_hi(u.x);
    float a2 = bf_lo(u.y), a3 = bf_hi(u.y);
    int2 rp = rp2[node];
    int e = rp.x, end = rp.y;                       // end-e is a multiple of 8
    for (; e < end; e += 8) {
        const uint4* cp = (const uint4*)(csr + e);  // 16B-aligned (8-padded rows)
        uint4 c0 = cp[0], c1 = cp[1];               // 8 indices, broadcast loads
        unsigned idx[8] = {c0.x, c0.y, c0.z, c0.w, c1.x, c1.y, c1.z, c1.w};
#pragma unroll
        for (int j = 0; j < 8; ++j) {
            uint2 v = src[(size_t)idx[j] * 32 + off];
            a0 += bf_lo(v.x); a1 += bf_hi(v.x);
            a2 += bf_lo(v.y); a3 += bf_hi(v.y);
        }
    }
    float s = scale[node];
    uint2 o; o.x = pack2(s * a0, s * a1); o.y = pack2(s * a2, s * a3);
    dst[(size_t)(node + 1) * 32 + off] = o;
}

// ---------------- MFMA GEMM + bias + log_softmax ----------------
// Rounds 4-8 empirical law: this kernel's HBM-visible traffic scales with GRID
// SIZE, not store shape (512: 63 MB ideal / 1024: 242 MB / 1563: 306 MB;
// identical at scattered, nontemporal, and LDS-staged full-line stores). The
// concurrency-driven traffic penalty exceeds any latency-hiding gain, so the
// minimum-traffic point grid=512 (2 blocks/CU) is the operating point. DO NOT
// raise the grid or occupancy here without re-measuring FETCH/WRITE.

__global__ __launch_bounds__(256) void k_gemm_lsm_mfma(const unsigned short* __restrict__ h,
                                                       const unsigned short* __restrict__ wbf,
                                                       const float* __restrict__ b,
                                                       float* __restrict__ out) {
    int tid = threadIdx.x;
    int lane = tid & 63;
    int wave = tid >> 6;
    int m = lane & 15, quad = lane >> 4;

    float bv[8];
#pragma unroll
    for (int t = 0; t < 8; ++t) bv[t] = b[16 * t + m];

    const int ngroups = (N_NODES + 63) / 64;        // 1563 groups of 64 nodes
    for (int g = blockIdx.x; g < ngroups; g += gridDim.x) {
        int gbase = g * 64 + wave * 16;
        int nodeA = gbase + m;
        int node_c = nodeA < N_NODES ? nodeA : N_NODES - 1;
        short8 a[4];
#pragma unroll
        for (int ks = 0; ks < 4; ++ks)
            a[ks] = *(const short8*)(h + (size_t)node_c * 128 + ks * 32 + quad * 8);
        floatx4 acc[8];
#pragma unroll
        for (int t = 0; t < 8; ++t) acc[t] = (floatx4){bv[t], bv[t], bv[t], bv[t]};
        // B fragment (t,ks): lane holds W[16t+m][ks*32+quad*8 .. +8) as bf16,
        // read from the 32 KB wbf image (L1/L2-hot across groups).
#pragma unroll
        for (int t = 0; t < 8; ++t) {
#pragma unroll
            for (int ks = 0; ks < 4; ++ks) {
                short8 bf = *(const short8*)(wbf + (size_t)(16 * t + m) * 128 + ks * 32 + quad * 8);
                acc[t] = __builtin_amdgcn_mfma_f32_16x16x32_bf16(a[ks], bf, acc[t], 0, 0, 0);
            }
        }

        // D layout: row = gbase + quad*4 + r, col = 16t + m
#pragma unroll
        for (int r = 0; r < 4; ++r) {
            float mx = acc[0][r];
#pragma unroll
            for (int t = 1; t < 8; ++t) mx = fmaxf(mx, acc[t][r]);
#pragma unroll
            for (int msk = 1; msk < 16; msk <<= 1) mx = fmaxf(mx, __shfl_xor(mx, msk));
            float sm = 0.f;
#pragma unroll
            for (int t = 0; t < 8; ++t) sm += __expf(acc[t][r] - mx);
#pragma unroll
            for (int msk = 1; msk < 16; msk <<= 1) sm += __shfl_xor(sm, msk);
            float l = mx + __logf(sm);
            int rown = gbase + quad * 4 + r;
            if (rown < N_NODES) {
                float* op = out + (size_t)rown * 128 + m;
#pragma unroll
                for (int t = 0; t < 8; ++t) op[16 * t] = acc[t][r] - l;
            }
        }
    }
}

// ---------------- launch ----------------

extern "C" void kernel_launch(void* const* d_in, const int* in_sizes, int n_in,
                              void* d_out, int out_size, void* d_ws, size_t ws_size,
                              hipStream_t stream) {
    const float* x = (const float*)d_in[0];
    const float* W = (const float*)d_in[1];
    const float* b = (const float*)d_in[2];
    const int* edge = (const int*)d_in[3];
    const int* row = edge;             // source nodes j
    const int* col = edge + N_EDGES;   // target nodes i
    float* out = (float*)d_out;

    // workspace layout (4B word offsets)
    int*      bcnt  = (int*)d_ws;                     // NBUCK padded ctrs (50KB) - only memset
    float*    dinv  = (float*)(bcnt + NBUCK * CPAD + 256);
    float*    dinv2 = dinv + 102400;                  // 100k
    int2*     rp2   = (int2*)(dinv2 + 102400);        // 100k (start,end)
    unsigned* csr   = (unsigned*)(rp2 + 102400);      // NBUCK*BSPAN = 1.6M (6.4 MB)
    uint2*    xb    = (uint2*)(csr + (size_t)NBUCK * BSPAN);  // (N+1)*32 uint2 = 25.6 MB
    uint2*    h1b   = xb + 32 * (N_NODES + 1);        // (N+1)*32 uint2
    uint2*    h2b   = xb;                             // reuse: xb dead after hop 1
    // stage aliases h1b past its zero-row (h1b is only written by k_hop #1,
    // which launches after k_build has consumed stage; stream order serializes).
    unsigned* stage = (unsigned*)(h1b + 32);          // NBUCK*SCAP*4 = 4.8 MB
    uint2*    wbf   = h1b + 32 * (N_NODES + 1);       // 4096 uint2 = 32 KB bf16 W

    int nb_prep = (N_NODES * 32 + 255) / 256;         // 12500

    (void)hipMemsetAsync(bcnt, 0, (size_t)NBUCK * CPAD * 4, stream);   // 50 KB
    k_fill3<<<FILL_BLOCKS, 256, 0, stream>>>(row, col, bcnt, stage);
    k_build<<<NBUCK, 256, 0, stream>>>(bcnt, stage, csr, rp2, dinv, dinv2);
    k_prep<<<nb_prep, 256, 0, stream>>>((const float4*)x, dinv, (const float4*)W, wbf, xb, h1b);

    int hop_blocks = (N_NODES / 2 * 64) / 256;        // 12500: one wave per 2 nodes
    k_hop<<<hop_blocks, 256, 0, stream>>>(rp2, csr, dinv2, xb, h1b);   // -> y1
    k_hop<<<hop_blocks, 256, 0, stream>>>(rp2, csr, dinv, h1b, h2b);   // -> h2

    k_gemm_lsm_mfma<<<512, 256, 0, stream>>>((const unsigned short*)(h2b + 32),
                                             (const unsigned short*)wbf, b, out);
}